// Round 19
// baseline (2706.214 us; speedup 1.0000x reference)
//
#include <hip/hip_runtime.h>
#include <hip/hip_bf16.h>
#include <math.h>

namespace {

constexpr int BB  = 4;
constexpr int NN  = 8192;
constexpr int IND = 32;
constexpr int NPT = 1024;
constexpr int NSM = 32;
constexpr int SACOLS = BB * NPT * NSM;   // 131072
constexpr int FPCOLS = BB * NN;          // 32768
constexpr int CSTR = 132;                // stats stride (scale [0..C), shift [CSTR..))

// ---- f64 helpers for ball-query / 3-NN (np-f64 decisions) ----
__device__ __forceinline__ double sqn3_f64(float x, float y, float z) {
#pragma clang fp contract(off)
    double dx = (double)x, dy = (double)y, dz = (double)z;
    return (dx * dx + dy * dy) + dz * dz;
}
__device__ __forceinline__ double dot3_f64(float ax, float ay, float az,
                                           float bx, float by, float bz) {
#pragma clang fp contract(off)
    return ((double)ax * (double)bx + (double)ay * (double)by) + (double)az * (double)bz;
}
__device__ __forceinline__ double sqd_f64(double sa, double sb, double dot) {
#pragma clang fp contract(off)
    return (sa + sb) - 2.0 * dot;
}

// ---------------------------------------------------------------------------
// FPS v8: r17 structure (256 thr, 32 pts/thread, LDS point table, one
// barrier/step) with SLIMMED inner loop: f32 best tracking with inline-const
// slot index (cmp + 2 cndmask per elem), u64 pack ONCE after the loop.
// Tie-break: within-thread strict > over ascending i keeps smallest idx
// (idx = tid + i*256 monotone in i); cross-thread u64 max with inverted idx
// = numpy first-max. f32 distances in jax op order (r14-validated).
// lax.scan emits PRE-update far: centers = [0, a1, ..., a1023].
// ---------------------------------------------------------------------------
__global__ __launch_bounds__(256)
void k_fps(const float* __restrict__ xyz, float* __restrict__ new_xyz)
{
#pragma clang fp contract(off)
    const int b   = blockIdx.x;
    const int tid = threadIdx.x;                 // 0..255
    const float* P = xyz + (size_t)b * NN * 3;

    __shared__ float sx[NN];                     // 32 KB
    __shared__ float sy[NN];                     // 32 KB
    __shared__ float sz[NN];                     // 32 KB
    __shared__ float ctrs[NPT * 3];              // 12 KB
    __shared__ unsigned long long wv[2][4];

    float px[32], py[32], pz[32], dd[32];
#pragma unroll
    for (int i = 0; i < 32; ++i) {
        int p = tid + i * 256;
        float x = P[p * 3 + 0], y = P[p * 3 + 1], z = P[p * 3 + 2];
        px[i] = x; py[i] = y; pz[i] = z; dd[i] = 1e10f;
        sx[p] = x; sy[p] = y; sz[p] = z;
    }
    float cx = P[0], cy = P[1], cz = P[2];       // far = 0
    __syncthreads();                              // point table ready

    for (int t = 0; t < NPT; ++t) {
        if (tid == 0) {
            ctrs[t * 3 + 0] = cx;
            ctrs[t * 3 + 1] = cy;
            ctrs[t * 3 + 2] = cz;
        }
        if (t == NPT - 1) break;

        float bv = -1.0f;
        int   bi = 0;                             // slot index 0..31 (inline consts)
#pragma unroll
        for (int i = 0; i < 32; ++i) {
            float dx = px[i] - cx;
            float dy = py[i] - cy;
            float dz = pz[i] - cz;
            float d  = (dx * dx + dy * dy) + dz * dz;   // jax: (x2+y2)+z2
            float nd = fminf(dd[i], d);
            dd[i] = nd;
            if (nd > bv) { bv = nd; bi = i; }     // ascending i -> first max
        }
        // pack once: (dist bits << 32) | (NN-1 - global_idx)
        unsigned long long best =
            ((unsigned long long)__float_as_uint(bv) << 32) |
            (unsigned)(NN - 1 - (tid + bi * 256));
        // wave (64-lane) u64 max
        for (int off = 32; off > 0; off >>= 1) {
            unsigned long long o = __shfl_down(best, off);
            best = (o > best) ? o : best;
        }
        const int buf = t & 1;
        if ((tid & 63) == 0) wv[buf][tid >> 6] = best;
        __syncthreads();
        unsigned long long w0 = wv[buf][0];
#pragma unroll
        for (int k = 1; k < 4; ++k) {
            unsigned long long wk = wv[buf][k];
            w0 = (wk > w0) ? wk : w0;
        }
        const int idx = (NN - 1) - (int)(unsigned)(w0 & 0xFFFFFFFFull);
        cx = sx[idx]; cy = sy[idx]; cz = sz[idx];
        // next step writes wv[buf^1] — no second barrier needed
    }

    __syncthreads();   // ctrs complete
    float* O = new_xyz + (size_t)b * NPT * 3;
    for (int i = tid; i < NPT * 3; i += 256) O[i] = ctrs[i];
}

// ---------------------------------------------------------------------------
// Ball query: one wave/center, f64 test, first-32-hits, pad with first hit.
// ---------------------------------------------------------------------------
__global__ __launch_bounds__(256)
void k_ballquery(const float* __restrict__ xyz, const float* __restrict__ new_xyz,
                 int* __restrict__ gidx)
{
    const int wv   = threadIdx.x >> 6;
    const int lane = threadIdx.x & 63;
    const int cid  = blockIdx.x * 4 + wv;
    const int b    = cid >> 10;
    const float* P = xyz + (size_t)b * NN * 3;

    const float cx = new_xyz[(size_t)cid * 3 + 0];
    const float cy = new_xyz[(size_t)cid * 3 + 1];
    const float cz = new_xyz[(size_t)cid * 3 + 2];
    const double sa = sqn3_f64(cx, cy, cz);
    const double R2 = 0.2 * 0.2;

    int cnt = 0;
    int firstidx = -1;
    int* G = gidx + (size_t)cid * NSM;

    for (int base = 0; base < NN && cnt < NSM; base += 64) {
        int p = base + lane;
        float x = P[p * 3 + 0], y = P[p * 3 + 1], z = P[p * 3 + 2];
        double sb  = sqn3_f64(x, y, z);
        double dot = dot3_f64(cx, cy, cz, x, y, z);
        double d2  = sqd_f64(sa, sb, dot);
        bool hit = d2 < R2;
        unsigned long long m = __ballot(hit);
        if (firstidx < 0 && m != 0ull) firstidx = base + __builtin_ctzll(m);
        int before = __popcll(m & ((1ull << lane) - 1ull));
        int pos = cnt + before;
        if (hit && pos < NSM) G[pos] = p;
        cnt += __popcll(m);
    }
    if (firstidx < 0) firstidx = 0;
    if (cnt < NSM) {
        for (int j = cnt + lane; j < NSM; j += 64) G[j] = firstidx;
    }
}

// ---------------------------------------------------------------------------
// h0 [35][SACOLS]: ch0-2 = (gathered - center)/0.2, ch3-34 = features.
// ---------------------------------------------------------------------------
__global__ __launch_bounds__(256)
void k_group(const float* __restrict__ xyz, const float* __restrict__ feats,
             const float* __restrict__ new_xyz, const int* __restrict__ gidx,
             float* __restrict__ h0)
{
    const int col = blockIdx.x * 256 + threadIdx.x;
    const int cid = col >> 5;
    const int b   = col >> 15;
    const int g   = gidx[col];
    const float* Pt = xyz + ((size_t)b * NN + g) * 3;
    const float* Ct = new_xyz + (size_t)cid * 3;
    h0[(size_t)0 * SACOLS + col] = __fsub_rn(Pt[0], Ct[0]) / 0.2f;
    h0[(size_t)1 * SACOLS + col] = __fsub_rn(Pt[1], Ct[1]) / 0.2f;
    h0[(size_t)2 * SACOLS + col] = __fsub_rn(Pt[2], Ct[2]) / 0.2f;
    const float* FT = feats + (size_t)b * IND * NN;
    for (int c = 0; c < IND; ++c)
        h0[(size_t)(3 + c) * SACOLS + col] = FT[(size_t)c * NN + g];
}

// ---------------------------------------------------------------------------
// Tiled GEMM v1 + FUSED BN-stats epilogue: each block reduces its own Z tile
// (exact written values) to per-channel (sum, sumsq) f64 partials via
// in-wave f64 shfl tree (deterministic), writes part[c*nblk + blockIdx.x].
// BN of PREVIOUS layer folded into the load.
// ---------------------------------------------------------------------------
__global__ __launch_bounds__(256)
void k_conv(const float* __restrict__ X, const float* __restrict__ W,
            const float* __restrict__ bias,
            const float* __restrict__ scale, const float* __restrict__ shift,
            float* __restrict__ Z, double* __restrict__ part,
            int Cin, int Cout, int ncol, int apply_act)
{
    __shared__ __align__(16) float Xs[32][64];
    __shared__ float Ws[64][33];
    const int tid  = threadIdx.x;
    const int col0 = blockIdx.x * 64;
    const int o0   = blockIdx.y * 64;
    const int tx   = tid & 15;
    const int ty   = tid >> 4;
    float acc[4][4] = {};

    for (int kk = 0; kk < Cin; kk += 32) {
#pragma unroll
        for (int i = 0; i < 8; ++i) {
            int idx = tid + i * 256;
            int c = idx >> 6, cc = idx & 63;
            int ch = kk + c;
            float v = 0.0f;
            if (ch < Cin) {
                v = X[(size_t)ch * ncol + col0 + cc];
                if (apply_act) v = fmaxf(fmaf(v, scale[ch], shift[ch]), 0.0f);
            }
            Xs[c][cc] = v;
        }
#pragma unroll
        for (int i = 0; i < 8; ++i) {
            int idx = tid + i * 256;
            int o = idx >> 5, c = idx & 31;
            int ch = kk + c, oo = o0 + o;
            Ws[o][c] = (ch < Cin && oo < Cout) ? W[(size_t)oo * Cin + ch] : 0.0f;
        }
        __syncthreads();
#pragma unroll
        for (int c = 0; c < 32; ++c) {
            const float4 xv = *reinterpret_cast<const float4*>(&Xs[c][tx * 4]);
            float w0 = Ws[ty * 4 + 0][c];
            float w1 = Ws[ty * 4 + 1][c];
            float w2 = Ws[ty * 4 + 2][c];
            float w3 = Ws[ty * 4 + 3][c];
            acc[0][0] = fmaf(w0, xv.x, acc[0][0]); acc[0][1] = fmaf(w0, xv.y, acc[0][1]);
            acc[0][2] = fmaf(w0, xv.z, acc[0][2]); acc[0][3] = fmaf(w0, xv.w, acc[0][3]);
            acc[1][0] = fmaf(w1, xv.x, acc[1][0]); acc[1][1] = fmaf(w1, xv.y, acc[1][1]);
            acc[1][2] = fmaf(w1, xv.z, acc[1][2]); acc[1][3] = fmaf(w1, xv.w, acc[1][3]);
            acc[2][0] = fmaf(w2, xv.x, acc[2][0]); acc[2][1] = fmaf(w2, xv.y, acc[2][1]);
            acc[2][2] = fmaf(w2, xv.z, acc[2][2]); acc[2][3] = fmaf(w2, xv.w, acc[2][3]);
            acc[3][0] = fmaf(w3, xv.x, acc[3][0]); acc[3][1] = fmaf(w3, xv.y, acc[3][1]);
            acc[3][2] = fmaf(w3, xv.z, acc[3][2]); acc[3][3] = fmaf(w3, xv.w, acc[3][3]);
        }
        __syncthreads();
    }
#pragma unroll
    for (int i = 0; i < 4; ++i) {
        int o = o0 + ty * 4 + i;
        if (o >= Cout) break;
        float bz = bias ? bias[o] : 0.0f;
        float v0 = acc[i][0] + bz;
        float v1 = acc[i][1] + bz;
        float v2 = acc[i][2] + bz;
        float v3 = acc[i][3] + bz;
        float* zp = Z + (size_t)o * ncol + col0 + tx * 4;
        zp[0] = v0; zp[1] = v1; zp[2] = v2; zp[3] = v3;

        if (part) {
            // f64 partial sums over this thread's 4 cols, reduce across 16 tx
            double s = ((double)v0 + (double)v1) + ((double)v2 + (double)v3);
            double q = ((double)v0 * v0 + (double)v1 * v1)
                     + ((double)v2 * v2 + (double)v3 * v3);
            for (int off = 8; off > 0; off >>= 1) {
                s += __shfl_down(s, off);
                q += __shfl_down(q, off);
            }
            if (tx == 0) {
                const int nblk = ncol >> 6;
                part[((size_t)o * nblk + blockIdx.x) * 2 + 0] = s;
                part[((size_t)o * nblk + blockIdx.x) * 2 + 1] = q;
            }
        }
    }
}

// ---------------------------------------------------------------------------
// Stats finalize: sum per-channel block partials (fixed order, 2 thr/channel)
// -> folded scale/shift.
// ---------------------------------------------------------------------------
__global__ void k_stats_final(const double* __restrict__ part,
                              const float* __restrict__ gamma, const float* __restrict__ beta,
                              float* __restrict__ sc_out, float* __restrict__ sh_out,
                              int C, int nblk, double n)
{
    const int t = threadIdx.x;      // 0..255
    const int c = t >> 1;
    const int h = t & 1;
    if (c >= C) return;
    const int half = nblk >> 1;
    const double* p = part + ((size_t)c * nblk + (size_t)h * half) * 2;
    double s = 0.0, q = 0.0;
    for (int i = 0; i < half; ++i) { s += p[i * 2 + 0]; q += p[i * 2 + 1]; }
    double so = __shfl_down(s, 1);
    double qo = __shfl_down(q, 1);
    if (h == 0) {
        s += so; q += qo;
        double mean = s / n;
        double var  = q / n - mean * mean;
        double scl  = (double)gamma[c] / sqrt(var + 1e-5);
        sc_out[c] = (float)scl;
        sh_out[c] = (float)((double)beta[c] - mean * scl);
    }
}

// ---------------------------------------------------------------------------
// feat_sa[c][bp] = max_s relu(bn(Z2[c][bp*32+s]))
// ---------------------------------------------------------------------------
__global__ __launch_bounds__(256)
void k_maxpool(const float* __restrict__ Z, const float* __restrict__ sc,
               const float* __restrict__ sh, float* __restrict__ feat)
{
    const int idx = blockIdx.x * 256 + threadIdx.x;
    const int bp  = idx & 4095;
    const int c   = idx >> 12;
    const float s = sc[c], h = sh[c];
    const float* p = Z + (size_t)c * SACOLS + (size_t)bp * 32;
    float m = 0.0f;
    for (int ss = 0; ss < 32; ++ss) m = fmaxf(m, fmaxf(fmaf(p[ss], s, h), 0.0f));
    feat[(size_t)c * (BB * NPT) + bp] = m;
}

// ---------------------------------------------------------------------------
// 3-NN over 1024 centers (f64) + inverse-distance weights.
// ---------------------------------------------------------------------------
__global__ __launch_bounds__(256)
void k_3nn(const float* __restrict__ xyz, const float* __restrict__ new_xyz,
           int* __restrict__ idx3, float* __restrict__ w3)
{
    const int gid = blockIdx.x * 256 + threadIdx.x;
    const int b = gid >> 13;
    __shared__ float  cxs[NPT];
    __shared__ float  cys[NPT];
    __shared__ float  czs[NPT];
    __shared__ double cns[NPT];
    const float* C = new_xyz + (size_t)b * NPT * 3;
    for (int i = threadIdx.x; i < NPT; i += 256) {
        float x = C[i * 3], y = C[i * 3 + 1], z = C[i * 3 + 2];
        cxs[i] = x; cys[i] = y; czs[i] = z; cns[i] = sqn3_f64(x, y, z);
    }
    __syncthreads();

    const float* P = xyz + (size_t)gid * 3;
    const float px = P[0], py = P[1], pz = P[2];
    const double sb = sqn3_f64(px, py, pz);
    double d0 = 1e30, d1 = 1e30, d2v = 1e30;
    int    i0 = 0, i1 = 0, i2 = 0;
    for (int m = 0; m < NPT; ++m) {
        double dot = dot3_f64(px, py, pz, cxs[m], cys[m], czs[m]);
        double d   = sqd_f64(sb, cns[m], dot);
        if (d < d0)       { d2v = d1; i2 = i1; d1 = d0; i1 = i0; d0 = d; i0 = m; }
        else if (d < d1)  { d2v = d1; i2 = i1; d1 = d;  i1 = m; }
        else if (d < d2v) { d2v = d;  i2 = m; }
    }
    {
#pragma clang fp contract(off)
        double e0 = fmax(d0, 0.0), e1 = fmax(d1, 0.0), e2 = fmax(d2v, 0.0);
        double r0 = 1.0 / (e0 + 1e-8);
        double r1 = 1.0 / (e1 + 1e-8);
        double r2 = 1.0 / (e2 + 1e-8);
        double rs = (r0 + r1) + r2;
        idx3[(size_t)gid * 3 + 0] = i0; idx3[(size_t)gid * 3 + 1] = i1; idx3[(size_t)gid * 3 + 2] = i2;
        w3[(size_t)gid * 3 + 0] = (float)(r0 / rs);
        w3[(size_t)gid * 3 + 1] = (float)(r1 / rs);
        w3[(size_t)gid * 3 + 2] = (float)(r2 / rs);
    }
}

// ---------------------------------------------------------------------------
// hfp [160][FPCOLS]: ch0-127 interp(feat_sa), ch128-159 features.
// ---------------------------------------------------------------------------
__global__ __launch_bounds__(256)
void k_hfp(const float* __restrict__ feats, const float* __restrict__ feat_sa,
           const int* __restrict__ idx3, const float* __restrict__ w3,
           float* __restrict__ hfp)
{
    const int col = blockIdx.x * 256 + threadIdx.x;
    const int b = col >> 13, n = col & 8191;
    const int ia = idx3[(size_t)col * 3 + 0];
    const int ib = idx3[(size_t)col * 3 + 1];
    const int ic = idx3[(size_t)col * 3 + 2];
    const float wa = w3[(size_t)col * 3 + 0];
    const float wb = w3[(size_t)col * 3 + 1];
    const float wc = w3[(size_t)col * 3 + 2];
    const int cb = b * NPT;
    for (int o = 0; o < 128; ++o) {
        const float* f = feat_sa + (size_t)o * (BB * NPT) + cb;
        hfp[(size_t)o * FPCOLS + col] = f[ia] * wa + f[ib] * wb + f[ic] * wc;
    }
    const float* FT = feats + (size_t)b * IND * NN;
    for (int c = 0; c < IND; ++c)
        hfp[(size_t)(128 + c) * FPCOLS + col] = FT[(size_t)c * NN + n];
}

// ---------------------------------------------------------------------------
// Final outputs — FLOAT32.
// Layout: vote_xyz[98304] | offset[98304] | score[32768] | vf[4194304].
// ---------------------------------------------------------------------------
__global__ __launch_bounds__(256)
void k_outputs(const float* __restrict__ xyz, const float* __restrict__ Zc3,
               const float* __restrict__ Zf1, const float* __restrict__ sc4,
               const float* __restrict__ sh4, float* __restrict__ out)
{
    const int col = blockIdx.x * 256 + threadIdx.x;
    const float n0 = Zc3[(size_t)0 * FPCOLS + col];
    const float n1 = Zc3[(size_t)1 * FPCOLS + col];
    const float n2 = Zc3[(size_t)2 * FPCOLS + col];
    const float n3 = Zc3[(size_t)3 * FPCOLS + col];
    const float* P = xyz + (size_t)col * 3;

    float* o_vxyz = out;
    float* o_off  = out + 98304;
    float* o_sc   = out + 196608;
    float* o_vf   = out + 229376;

    o_off[(size_t)col * 3 + 0] = n0;
    o_off[(size_t)col * 3 + 1] = n1;
    o_off[(size_t)col * 3 + 2] = n2;
    o_vxyz[(size_t)col * 3 + 0] = __fadd_rn(P[0], n0);
    o_vxyz[(size_t)col * 3 + 1] = __fadd_rn(P[1], n1);
    o_vxyz[(size_t)col * 3 + 2] = __fadd_rn(P[2], n2);
    o_sc[col] = 1.0f / (1.0f + expf(-n3));

    float sumsq = 0.0f;
    for (int c = 0; c < 128; ++c) {
        float seed = fmaxf(fmaf(Zf1[(size_t)c * FPCOLS + col], sc4[c], sh4[c]), 0.0f);
        float v = seed + Zc3[(size_t)(4 + c) * FPCOLS + col];
        sumsq = fmaf(v, v, sumsq);
    }
    float inv = 1.0f / fmaxf(sqrtf(sumsq), 1e-12f);
    for (int c = 0; c < 128; ++c) {
        float seed = fmaxf(fmaf(Zf1[(size_t)c * FPCOLS + col], sc4[c], sh4[c]), 0.0f);
        float v = seed + Zc3[(size_t)(4 + c) * FPCOLS + col];
        o_vf[(size_t)col * 128 + c] = v * inv;
    }
}

__global__ void k_sentinel(float* out)
{
    if (threadIdx.x < 8) out[threadIdx.x] = 12345.0f;
}

} // namespace

extern "C" void kernel_launch(void* const* d_in, const int* in_sizes, int n_in,
                              void* d_out, int out_size, void* d_ws, size_t ws_size,
                              hipStream_t stream)
{
    (void)in_sizes; (void)n_in; (void)out_size;
    const float* xyz   = (const float*)d_in[0];
    const float* feats = (const float*)d_in[1];
    const float* W_sa0 = (const float*)d_in[2];
    const float* g_sa0 = (const float*)d_in[3];
    const float* b_sa0 = (const float*)d_in[4];
    const float* W_sa1 = (const float*)d_in[5];
    const float* g_sa1 = (const float*)d_in[6];
    const float* b_sa1 = (const float*)d_in[7];
    const float* W_sa2 = (const float*)d_in[8];
    const float* g_sa2 = (const float*)d_in[9];
    const float* b_sa2 = (const float*)d_in[10];
    const float* W_fp0 = (const float*)d_in[11];
    const float* g_fp0 = (const float*)d_in[12];
    const float* b_fp0 = (const float*)d_in[13];
    const float* W_fp1 = (const float*)d_in[14];
    const float* g_fp1 = (const float*)d_in[15];
    const float* b_fp1 = (const float*)d_in[16];
    const float* Wc1   = (const float*)d_in[17];
    const float* bc1   = (const float*)d_in[18];
    const float* g1    = (const float*)d_in[19];
    const float* b1    = (const float*)d_in[20];
    const float* Wc2   = (const float*)d_in[21];
    const float* bc2   = (const float*)d_in[22];
    const float* g2    = (const float*)d_in[23];
    const float* b2    = (const float*)d_in[24];
    const float* Wc3   = (const float*)d_in[25];
    const float* bc3   = (const float*)d_in[26];

    char* ws = (char*)d_ws;
    size_t off = 0;
    auto alloc = [&](size_t bytes) -> size_t {
        size_t o = off;
        off += (bytes + 255) & ~(size_t)255;
        return o;
    };
    float*  new_xyz = (float*) (ws + alloc((size_t)BB * NPT * 3 * 4));
    int*    gidx    = (int*)   (ws + alloc((size_t)BB * NPT * NSM * 4));
    int*    idx3    = (int*)   (ws + alloc((size_t)FPCOLS * 3 * 4));
    float*  w3      = (float*) (ws + alloc((size_t)FPCOLS * 3 * 4));
    double* part    = (double*)(ws + alloc((size_t)128 * 2048 * 2 * 8));   // per-block partials
    float*  stats   = (float*) (ws + alloc((size_t)7 * 2 * CSTR * 4));
    float*  regA    = (float*) (ws + alloc((size_t)35 * SACOLS * 4));   // h0, later Zc3
    float*  ZA      = (float*) (ws + alloc((size_t)128 * SACOLS * 4));
    float*  ZB      = (float*) (ws + alloc((size_t)128 * SACOLS * 4));
    float*  feat_sa = (float*) (ws + alloc((size_t)128 * BB * NPT * 4));
    size_t required = off;

    if (ws_size < required) {
        k_sentinel<<<1, 64, 0, stream>>>((float*)d_out);
        return;
    }

    float* h0  = regA;
    float* Zc3 = regA;
    float* hfp = ZA;                          // 160*FPCOLS
    float* Zf0 = ZA + (size_t)160 * FPCOLS;   // 128*FPCOLS
    float* Zc1 = ZA + (size_t)(160 + 128) * FPCOLS;
    float* Zf1 = ZB;
    float* Zc2 = ZB + (size_t)128 * FPCOLS;

    float* st[7];
    for (int l = 0; l < 7; ++l) st[l] = stats + (size_t)l * 2 * CSTR;
    const double nSA = (double)SACOLS, nFP = (double)FPCOLS;
    const int nbSA = SACOLS / 64;   // 2048
    const int nbFP = FPCOLS / 64;   // 512

    // ---- geometry ----
    k_fps<<<BB, 256, 0, stream>>>(xyz, new_xyz);
    k_ballquery<<<(BB * NPT) / 4, 256, 0, stream>>>(xyz, new_xyz, gidx);
    k_group<<<SACOLS / 256, 256, 0, stream>>>(xyz, feats, new_xyz, gidx, h0);

    // ---- SA MLP (BN stats fused into conv epilogue) ----
    k_conv<<<dim3(SACOLS / 64, 2), 256, 0, stream>>>(h0, W_sa0, nullptr, nullptr, nullptr, ZA, part, 35, 128, SACOLS, 0);
    k_stats_final<<<1, 256, 0, stream>>>(part, g_sa0, b_sa0, st[0], st[0] + CSTR, 128, nbSA, nSA);

    k_conv<<<dim3(SACOLS / 64, 2), 256, 0, stream>>>(ZA, W_sa1, nullptr, st[0], st[0] + CSTR, ZB, part, 128, 128, SACOLS, 1);
    k_stats_final<<<1, 256, 0, stream>>>(part, g_sa1, b_sa1, st[1], st[1] + CSTR, 128, nbSA, nSA);

    k_conv<<<dim3(SACOLS / 64, 2), 256, 0, stream>>>(ZB, W_sa2, nullptr, st[1], st[1] + CSTR, ZA, part, 128, 128, SACOLS, 1);
    k_stats_final<<<1, 256, 0, stream>>>(part, g_sa2, b_sa2, st[2], st[2] + CSTR, 128, nbSA, nSA);

    k_maxpool<<<(128 * BB * NPT) / 256, 256, 0, stream>>>(ZA, st[2], st[2] + CSTR, feat_sa);

    // ---- 3-NN interpolation + concat ----
    k_3nn<<<FPCOLS / 256, 256, 0, stream>>>(xyz, new_xyz, idx3, w3);
    k_hfp<<<FPCOLS / 256, 256, 0, stream>>>(feats, feat_sa, idx3, w3, hfp);

    // ---- FP MLP + vote head ----
    k_conv<<<dim3(FPCOLS / 64, 2), 256, 0, stream>>>(hfp, W_fp0, nullptr, nullptr, nullptr, Zf0, part, 160, 128, FPCOLS, 0);
    k_stats_final<<<1, 256, 0, stream>>>(part, g_fp0, b_fp0, st[3], st[3] + CSTR, 128, nbFP, nFP);

    k_conv<<<dim3(FPCOLS / 64, 2), 256, 0, stream>>>(Zf0, W_fp1, nullptr, st[3], st[3] + CSTR, Zf1, part, 128, 128, FPCOLS, 1);
    k_stats_final<<<1, 256, 0, stream>>>(part, g_fp1, b_fp1, st[4], st[4] + CSTR, 128, nbFP, nFP);

    k_conv<<<dim3(FPCOLS / 64, 2), 256, 0, stream>>>(Zf1, Wc1, bc1, st[4], st[4] + CSTR, Zc1, part, 128, 128, FPCOLS, 1);
    k_stats_final<<<1, 256, 0, stream>>>(part, g1, b1, st[5], st[5] + CSTR, 128, nbFP, nFP);

    k_conv<<<dim3(FPCOLS / 64, 2), 256, 0, stream>>>(Zc1, Wc2, bc2, st[5], st[5] + CSTR, Zc2, part, 128, 128, FPCOLS, 1);
    k_stats_final<<<1, 256, 0, stream>>>(part, g2, b2, st[6], st[6] + CSTR, 128, nbFP, nFP);

    k_conv<<<dim3(FPCOLS / 64, 3), 256, 0, stream>>>(Zc2, Wc3, bc3, st[6], st[6] + CSTR, Zc3, nullptr, 128, 132, FPCOLS, 1);

    // ---- outputs (FLOAT32) ----
    k_outputs<<<FPCOLS / 256, 256, 0, stream>>>(xyz, Zc3, Zf1, st[4], st[4] + CSTR, (float*)d_out);
}

// Round 20
// 2143.320 us; speedup vs baseline: 1.2626x; 1.2626x over previous
//
#include <hip/hip_runtime.h>
#include <hip/hip_bf16.h>
#include <math.h>

namespace {

constexpr int BB  = 4;
constexpr int NN  = 8192;
constexpr int IND = 32;
constexpr int NPT = 1024;
constexpr int NSM = 32;
constexpr int SACOLS = BB * NPT * NSM;   // 131072
constexpr int FPCOLS = BB * NN;          // 32768
constexpr int CSTR = 132;                // stats stride (scale [0..C), shift [CSTR..))

// ---- f64 helpers for ball-query / 3-NN (np-f64 decisions) ----
__device__ __forceinline__ double sqn3_f64(float x, float y, float z) {
#pragma clang fp contract(off)
    double dx = (double)x, dy = (double)y, dz = (double)z;
    return (dx * dx + dy * dy) + dz * dz;
}
__device__ __forceinline__ double dot3_f64(float ax, float ay, float az,
                                           float bx, float by, float bz) {
#pragma clang fp contract(off)
    return ((double)ax * (double)bx + (double)ay * (double)by) + (double)az * (double)bz;
}
__device__ __forceinline__ double sqd_f64(double sa, double sb, double dot) {
#pragma clang fp contract(off)
    return (sa + sb) - 2.0 * dot;
}

// ---------------------------------------------------------------------------
// FPS v7 (r17/r18-validated, 1100 us): 256 threads, 32 pts/thread,
// u64-packed (dist,idx) max, f32 distances in jax op order, centers staged
// in LDS. lax.scan emits PRE-update far: centers = [0, a1, ..., a1023].
// ---------------------------------------------------------------------------
__global__ __launch_bounds__(256)
void k_fps(const float* __restrict__ xyz, float* __restrict__ new_xyz)
{
#pragma clang fp contract(off)
    const int b   = blockIdx.x;
    const int tid = threadIdx.x;                 // 0..255
    const float* P = xyz + (size_t)b * NN * 3;

    __shared__ float sx[NN];                     // 32 KB
    __shared__ float sy[NN];                     // 32 KB
    __shared__ float sz[NN];                     // 32 KB
    __shared__ float ctrs[NPT * 3];              // 12 KB
    __shared__ unsigned long long wv[2][4];

    float px[32], py[32], pz[32], dd[32];
#pragma unroll
    for (int i = 0; i < 32; ++i) {
        int p = tid + i * 256;
        float x = P[p * 3 + 0], y = P[p * 3 + 1], z = P[p * 3 + 2];
        px[i] = x; py[i] = y; pz[i] = z; dd[i] = 1e10f;
        sx[p] = x; sy[p] = y; sz[p] = z;
    }
    float cx = P[0], cy = P[1], cz = P[2];       // far = 0
    __syncthreads();                              // point table ready

    for (int t = 0; t < NPT; ++t) {
        if (tid == 0) {
            ctrs[t * 3 + 0] = cx;
            ctrs[t * 3 + 1] = cy;
            ctrs[t * 3 + 2] = cz;
        }
        if (t == NPT - 1) break;

        unsigned long long best = 0ull;
#pragma unroll
        for (int i = 0; i < 32; ++i) {
            float dx = px[i] - cx;
            float dy = py[i] - cy;
            float dz = pz[i] - cz;
            float d  = (dx * dx + dy * dy) + dz * dz;   // jax: (x2+y2)+z2
            float nd = fminf(dd[i], d);
            dd[i] = nd;
            unsigned int lo = (unsigned)(NN - 1) - (unsigned)(tid + i * 256);
            unsigned long long cand =
                ((unsigned long long)__float_as_uint(nd) << 32) | lo;
            best = (cand > best) ? cand : best;
        }
        // wave (64-lane) u64 max
        for (int off = 32; off > 0; off >>= 1) {
            unsigned long long o = __shfl_down(best, off);
            best = (o > best) ? o : best;
        }
        const int buf = t & 1;
        if ((tid & 63) == 0) wv[buf][tid >> 6] = best;
        __syncthreads();
        unsigned long long w0 = wv[buf][0];
#pragma unroll
        for (int k = 1; k < 4; ++k) {
            unsigned long long wk = wv[buf][k];
            w0 = (wk > w0) ? wk : w0;
        }
        const int idx = (NN - 1) - (int)(unsigned)(w0 & 0xFFFFFFFFull);
        cx = sx[idx]; cy = sy[idx]; cz = sz[idx];
        // next step writes wv[buf^1] — no second barrier needed
    }

    __syncthreads();   // ctrs complete
    float* O = new_xyz + (size_t)b * NPT * 3;
    for (int i = tid; i < NPT * 3; i += 256) O[i] = ctrs[i];
}

// ---------------------------------------------------------------------------
// Ball query: one wave/center, f64 test, first-32-hits, pad with first hit.
// ---------------------------------------------------------------------------
__global__ __launch_bounds__(256)
void k_ballquery(const float* __restrict__ xyz, const float* __restrict__ new_xyz,
                 int* __restrict__ gidx)
{
    const int wv   = threadIdx.x >> 6;
    const int lane = threadIdx.x & 63;
    const int cid  = blockIdx.x * 4 + wv;
    const int b    = cid >> 10;
    const float* P = xyz + (size_t)b * NN * 3;

    const float cx = new_xyz[(size_t)cid * 3 + 0];
    const float cy = new_xyz[(size_t)cid * 3 + 1];
    const float cz = new_xyz[(size_t)cid * 3 + 2];
    const double sa = sqn3_f64(cx, cy, cz);
    const double R2 = 0.2 * 0.2;

    int cnt = 0;
    int firstidx = -1;
    int* G = gidx + (size_t)cid * NSM;

    for (int base = 0; base < NN && cnt < NSM; base += 64) {
        int p = base + lane;
        float x = P[p * 3 + 0], y = P[p * 3 + 1], z = P[p * 3 + 2];
        double sb  = sqn3_f64(x, y, z);
        double dot = dot3_f64(cx, cy, cz, x, y, z);
        double d2  = sqd_f64(sa, sb, dot);
        bool hit = d2 < R2;
        unsigned long long m = __ballot(hit);
        if (firstidx < 0 && m != 0ull) firstidx = base + __builtin_ctzll(m);
        int before = __popcll(m & ((1ull << lane) - 1ull));
        int pos = cnt + before;
        if (hit && pos < NSM) G[pos] = p;
        cnt += __popcll(m);
    }
    if (firstidx < 0) firstidx = 0;
    if (cnt < NSM) {
        for (int j = cnt + lane; j < NSM; j += 64) G[j] = firstidx;
    }
}

// ---------------------------------------------------------------------------
// h0 [35][SACOLS]: ch0-2 = (gathered - center)/0.2, ch3-34 = features.
// ---------------------------------------------------------------------------
__global__ __launch_bounds__(256)
void k_group(const float* __restrict__ xyz, const float* __restrict__ feats,
             const float* __restrict__ new_xyz, const int* __restrict__ gidx,
             float* __restrict__ h0)
{
    const int col = blockIdx.x * 256 + threadIdx.x;
    const int cid = col >> 5;
    const int b   = col >> 15;
    const int g   = gidx[col];
    const float* Pt = xyz + ((size_t)b * NN + g) * 3;
    const float* Ct = new_xyz + (size_t)cid * 3;
    h0[(size_t)0 * SACOLS + col] = __fsub_rn(Pt[0], Ct[0]) / 0.2f;
    h0[(size_t)1 * SACOLS + col] = __fsub_rn(Pt[1], Ct[1]) / 0.2f;
    h0[(size_t)2 * SACOLS + col] = __fsub_rn(Pt[2], Ct[2]) / 0.2f;
    const float* FT = feats + (size_t)b * IND * NN;
    for (int c = 0; c < IND; ++c)
        h0[(size_t)(3 + c) * SACOLS + col] = FT[(size_t)c * NN + g];
}

// ---------------------------------------------------------------------------
// Tiled GEMM v1 + fused BN-stats epilogue (r19): per-block (sum,sumsq) f64
// partials via in-wave f64 shfl tree, part[c*nblk + blockIdx.x].
// BN of PREVIOUS layer folded into the load.
// ---------------------------------------------------------------------------
__global__ __launch_bounds__(256)
void k_conv(const float* __restrict__ X, const float* __restrict__ W,
            const float* __restrict__ bias,
            const float* __restrict__ scale, const float* __restrict__ shift,
            float* __restrict__ Z, double* __restrict__ part,
            int Cin, int Cout, int ncol, int apply_act)
{
    __shared__ __align__(16) float Xs[32][64];
    __shared__ float Ws[64][33];
    const int tid  = threadIdx.x;
    const int col0 = blockIdx.x * 64;
    const int o0   = blockIdx.y * 64;
    const int tx   = tid & 15;
    const int ty   = tid >> 4;
    float acc[4][4] = {};

    for (int kk = 0; kk < Cin; kk += 32) {
#pragma unroll
        for (int i = 0; i < 8; ++i) {
            int idx = tid + i * 256;
            int c = idx >> 6, cc = idx & 63;
            int ch = kk + c;
            float v = 0.0f;
            if (ch < Cin) {
                v = X[(size_t)ch * ncol + col0 + cc];
                if (apply_act) v = fmaxf(fmaf(v, scale[ch], shift[ch]), 0.0f);
            }
            Xs[c][cc] = v;
        }
#pragma unroll
        for (int i = 0; i < 8; ++i) {
            int idx = tid + i * 256;
            int o = idx >> 5, c = idx & 31;
            int ch = kk + c, oo = o0 + o;
            Ws[o][c] = (ch < Cin && oo < Cout) ? W[(size_t)oo * Cin + ch] : 0.0f;
        }
        __syncthreads();
#pragma unroll
        for (int c = 0; c < 32; ++c) {
            const float4 xv = *reinterpret_cast<const float4*>(&Xs[c][tx * 4]);
            float w0 = Ws[ty * 4 + 0][c];
            float w1 = Ws[ty * 4 + 1][c];
            float w2 = Ws[ty * 4 + 2][c];
            float w3 = Ws[ty * 4 + 3][c];
            acc[0][0] = fmaf(w0, xv.x, acc[0][0]); acc[0][1] = fmaf(w0, xv.y, acc[0][1]);
            acc[0][2] = fmaf(w0, xv.z, acc[0][2]); acc[0][3] = fmaf(w0, xv.w, acc[0][3]);
            acc[1][0] = fmaf(w1, xv.x, acc[1][0]); acc[1][1] = fmaf(w1, xv.y, acc[1][1]);
            acc[1][2] = fmaf(w1, xv.z, acc[1][2]); acc[1][3] = fmaf(w1, xv.w, acc[1][3]);
            acc[2][0] = fmaf(w2, xv.x, acc[2][0]); acc[2][1] = fmaf(w2, xv.y, acc[2][1]);
            acc[2][2] = fmaf(w2, xv.z, acc[2][2]); acc[2][3] = fmaf(w2, xv.w, acc[2][3]);
            acc[3][0] = fmaf(w3, xv.x, acc[3][0]); acc[3][1] = fmaf(w3, xv.y, acc[3][1]);
            acc[3][2] = fmaf(w3, xv.z, acc[3][2]); acc[3][3] = fmaf(w3, xv.w, acc[3][3]);
        }
        __syncthreads();
    }
#pragma unroll
    for (int i = 0; i < 4; ++i) {
        int o = o0 + ty * 4 + i;
        if (o >= Cout) break;
        float bz = bias ? bias[o] : 0.0f;
        float v0 = acc[i][0] + bz;
        float v1 = acc[i][1] + bz;
        float v2 = acc[i][2] + bz;
        float v3 = acc[i][3] + bz;
        float* zp = Z + (size_t)o * ncol + col0 + tx * 4;
        zp[0] = v0; zp[1] = v1; zp[2] = v2; zp[3] = v3;

        if (part) {
            double s = ((double)v0 + (double)v1) + ((double)v2 + (double)v3);
            double q = ((double)v0 * v0 + (double)v1 * v1)
                     + ((double)v2 * v2 + (double)v3 * v3);
            for (int off = 8; off > 0; off >>= 1) {
                s += __shfl_down(s, off);
                q += __shfl_down(q, off);
            }
            if (tx == 0) {
                const int nblk = ncol >> 6;
                part[((size_t)o * nblk + blockIdx.x) * 2 + 0] = s;
                part[((size_t)o * nblk + blockIdx.x) * 2 + 1] = q;
            }
        }
    }
}

// ---------------------------------------------------------------------------
// Stats finalize v2 (PARALLEL): one block per channel, 256 threads.
// Thread j sums partials j, j+256, ... (coalesced, fixed order), LDS tree.
// Deterministic.
// ---------------------------------------------------------------------------
__global__ __launch_bounds__(256)
void k_stats_final(const double* __restrict__ part,
                   const float* __restrict__ gamma, const float* __restrict__ beta,
                   float* __restrict__ sc_out, float* __restrict__ sh_out,
                   int nblk, double n)
{
    const int c = blockIdx.x;
    const int t = threadIdx.x;
    const double* p = part + (size_t)c * nblk * 2;
    double s = 0.0, q = 0.0;
    for (int i = t; i < nblk; i += 256) { s += p[i * 2 + 0]; q += p[i * 2 + 1]; }
    __shared__ double ss[256];
    __shared__ double qq[256];
    ss[t] = s; qq[t] = q;
    __syncthreads();
    for (int off = 128; off > 0; off >>= 1) {
        if (t < off) { ss[t] += ss[t + off]; qq[t] += qq[t + off]; }
        __syncthreads();
    }
    if (t == 0) {
        double mean = ss[0] / n;
        double var  = qq[0] / n - mean * mean;
        double scl  = (double)gamma[c] / sqrt(var + 1e-5);
        sc_out[c] = (float)scl;
        sh_out[c] = (float)((double)beta[c] - mean * scl);
    }
}

// ---------------------------------------------------------------------------
// feat_sa[c][bp] = max_s relu(bn(Z2[c][bp*32+s]))
// ---------------------------------------------------------------------------
__global__ __launch_bounds__(256)
void k_maxpool(const float* __restrict__ Z, const float* __restrict__ sc,
               const float* __restrict__ sh, float* __restrict__ feat)
{
    const int idx = blockIdx.x * 256 + threadIdx.x;
    const int bp  = idx & 4095;
    const int c   = idx >> 12;
    const float s = sc[c], h = sh[c];
    const float* p = Z + (size_t)c * SACOLS + (size_t)bp * 32;
    float m = 0.0f;
    for (int ss = 0; ss < 32; ++ss) m = fmaxf(m, fmaxf(fmaf(p[ss], s, h), 0.0f));
    feat[(size_t)c * (BB * NPT) + bp] = m;
}

// ---------------------------------------------------------------------------
// 3-NN over 1024 centers (f64) + inverse-distance weights.
// ---------------------------------------------------------------------------
__global__ __launch_bounds__(256)
void k_3nn(const float* __restrict__ xyz, const float* __restrict__ new_xyz,
           int* __restrict__ idx3, float* __restrict__ w3)
{
    const int gid = blockIdx.x * 256 + threadIdx.x;
    const int b = gid >> 13;
    __shared__ float  cxs[NPT];
    __shared__ float  cys[NPT];
    __shared__ float  czs[NPT];
    __shared__ double cns[NPT];
    const float* C = new_xyz + (size_t)b * NPT * 3;
    for (int i = threadIdx.x; i < NPT; i += 256) {
        float x = C[i * 3], y = C[i * 3 + 1], z = C[i * 3 + 2];
        cxs[i] = x; cys[i] = y; czs[i] = z; cns[i] = sqn3_f64(x, y, z);
    }
    __syncthreads();

    const float* P = xyz + (size_t)gid * 3;
    const float px = P[0], py = P[1], pz = P[2];
    const double sb = sqn3_f64(px, py, pz);
    double d0 = 1e30, d1 = 1e30, d2v = 1e30;
    int    i0 = 0, i1 = 0, i2 = 0;
    for (int m = 0; m < NPT; ++m) {
        double dot = dot3_f64(px, py, pz, cxs[m], cys[m], czs[m]);
        double d   = sqd_f64(sb, cns[m], dot);
        if (d < d0)       { d2v = d1; i2 = i1; d1 = d0; i1 = i0; d0 = d; i0 = m; }
        else if (d < d1)  { d2v = d1; i2 = i1; d1 = d;  i1 = m; }
        else if (d < d2v) { d2v = d;  i2 = m; }
    }
    {
#pragma clang fp contract(off)
        double e0 = fmax(d0, 0.0), e1 = fmax(d1, 0.0), e2 = fmax(d2v, 0.0);
        double r0 = 1.0 / (e0 + 1e-8);
        double r1 = 1.0 / (e1 + 1e-8);
        double r2 = 1.0 / (e2 + 1e-8);
        double rs = (r0 + r1) + r2;
        idx3[(size_t)gid * 3 + 0] = i0; idx3[(size_t)gid * 3 + 1] = i1; idx3[(size_t)gid * 3 + 2] = i2;
        w3[(size_t)gid * 3 + 0] = (float)(r0 / rs);
        w3[(size_t)gid * 3 + 1] = (float)(r1 / rs);
        w3[(size_t)gid * 3 + 2] = (float)(r2 / rs);
    }
}

// ---------------------------------------------------------------------------
// hfp [160][FPCOLS]: ch0-127 interp(feat_sa), ch128-159 features.
// ---------------------------------------------------------------------------
__global__ __launch_bounds__(256)
void k_hfp(const float* __restrict__ feats, const float* __restrict__ feat_sa,
           const int* __restrict__ idx3, const float* __restrict__ w3,
           float* __restrict__ hfp)
{
    const int col = blockIdx.x * 256 + threadIdx.x;
    const int b = col >> 13, n = col & 8191;
    const int ia = idx3[(size_t)col * 3 + 0];
    const int ib = idx3[(size_t)col * 3 + 1];
    const int ic = idx3[(size_t)col * 3 + 2];
    const float wa = w3[(size_t)col * 3 + 0];
    const float wb = w3[(size_t)col * 3 + 1];
    const float wc = w3[(size_t)col * 3 + 2];
    const int cb = b * NPT;
    for (int o = 0; o < 128; ++o) {
        const float* f = feat_sa + (size_t)o * (BB * NPT) + cb;
        hfp[(size_t)o * FPCOLS + col] = f[ia] * wa + f[ib] * wb + f[ic] * wc;
    }
    const float* FT = feats + (size_t)b * IND * NN;
    for (int c = 0; c < IND; ++c)
        hfp[(size_t)(128 + c) * FPCOLS + col] = FT[(size_t)c * NN + n];
}

// ---------------------------------------------------------------------------
// Final outputs — FLOAT32.
// Layout: vote_xyz[98304] | offset[98304] | score[32768] | vf[4194304].
// ---------------------------------------------------------------------------
__global__ __launch_bounds__(256)
void k_outputs(const float* __restrict__ xyz, const float* __restrict__ Zc3,
               const float* __restrict__ Zf1, const float* __restrict__ sc4,
               const float* __restrict__ sh4, float* __restrict__ out)
{
    const int col = blockIdx.x * 256 + threadIdx.x;
    const float n0 = Zc3[(size_t)0 * FPCOLS + col];
    const float n1 = Zc3[(size_t)1 * FPCOLS + col];
    const float n2 = Zc3[(size_t)2 * FPCOLS + col];
    const float n3 = Zc3[(size_t)3 * FPCOLS + col];
    const float* P = xyz + (size_t)col * 3;

    float* o_vxyz = out;
    float* o_off  = out + 98304;
    float* o_sc   = out + 196608;
    float* o_vf   = out + 229376;

    o_off[(size_t)col * 3 + 0] = n0;
    o_off[(size_t)col * 3 + 1] = n1;
    o_off[(size_t)col * 3 + 2] = n2;
    o_vxyz[(size_t)col * 3 + 0] = __fadd_rn(P[0], n0);
    o_vxyz[(size_t)col * 3 + 1] = __fadd_rn(P[1], n1);
    o_vxyz[(size_t)col * 3 + 2] = __fadd_rn(P[2], n2);
    o_sc[col] = 1.0f / (1.0f + expf(-n3));

    float sumsq = 0.0f;
    for (int c = 0; c < 128; ++c) {
        float seed = fmaxf(fmaf(Zf1[(size_t)c * FPCOLS + col], sc4[c], sh4[c]), 0.0f);
        float v = seed + Zc3[(size_t)(4 + c) * FPCOLS + col];
        sumsq = fmaf(v, v, sumsq);
    }
    float inv = 1.0f / fmaxf(sqrtf(sumsq), 1e-12f);
    for (int c = 0; c < 128; ++c) {
        float seed = fmaxf(fmaf(Zf1[(size_t)c * FPCOLS + col], sc4[c], sh4[c]), 0.0f);
        float v = seed + Zc3[(size_t)(4 + c) * FPCOLS + col];
        o_vf[(size_t)col * 128 + c] = v * inv;
    }
}

__global__ void k_sentinel(float* out)
{
    if (threadIdx.x < 8) out[threadIdx.x] = 12345.0f;
}

} // namespace

extern "C" void kernel_launch(void* const* d_in, const int* in_sizes, int n_in,
                              void* d_out, int out_size, void* d_ws, size_t ws_size,
                              hipStream_t stream)
{
    (void)in_sizes; (void)n_in; (void)out_size;
    const float* xyz   = (const float*)d_in[0];
    const float* feats = (const float*)d_in[1];
    const float* W_sa0 = (const float*)d_in[2];
    const float* g_sa0 = (const float*)d_in[3];
    const float* b_sa0 = (const float*)d_in[4];
    const float* W_sa1 = (const float*)d_in[5];
    const float* g_sa1 = (const float*)d_in[6];
    const float* b_sa1 = (const float*)d_in[7];
    const float* W_sa2 = (const float*)d_in[8];
    const float* g_sa2 = (const float*)d_in[9];
    const float* b_sa2 = (const float*)d_in[10];
    const float* W_fp0 = (const float*)d_in[11];
    const float* g_fp0 = (const float*)d_in[12];
    const float* b_fp0 = (const float*)d_in[13];
    const float* W_fp1 = (const float*)d_in[14];
    const float* g_fp1 = (const float*)d_in[15];
    const float* b_fp1 = (const float*)d_in[16];
    const float* Wc1   = (const float*)d_in[17];
    const float* bc1   = (const float*)d_in[18];
    const float* g1    = (const float*)d_in[19];
    const float* b1    = (const float*)d_in[20];
    const float* Wc2   = (const float*)d_in[21];
    const float* bc2   = (const float*)d_in[22];
    const float* g2    = (const float*)d_in[23];
    const float* b2    = (const float*)d_in[24];
    const float* Wc3   = (const float*)d_in[25];
    const float* bc3   = (const float*)d_in[26];

    char* ws = (char*)d_ws;
    size_t off = 0;
    auto alloc = [&](size_t bytes) -> size_t {
        size_t o = off;
        off += (bytes + 255) & ~(size_t)255;
        return o;
    };
    float*  new_xyz = (float*) (ws + alloc((size_t)BB * NPT * 3 * 4));
    int*    gidx    = (int*)   (ws + alloc((size_t)BB * NPT * NSM * 4));
    int*    idx3    = (int*)   (ws + alloc((size_t)FPCOLS * 3 * 4));
    float*  w3      = (float*) (ws + alloc((size_t)FPCOLS * 3 * 4));
    double* part    = (double*)(ws + alloc((size_t)128 * 2048 * 2 * 8));
    float*  stats   = (float*) (ws + alloc((size_t)7 * 2 * CSTR * 4));
    float*  regA    = (float*) (ws + alloc((size_t)35 * SACOLS * 4));   // h0, later Zc3
    float*  ZA      = (float*) (ws + alloc((size_t)128 * SACOLS * 4));
    float*  ZB      = (float*) (ws + alloc((size_t)128 * SACOLS * 4));
    float*  feat_sa = (float*) (ws + alloc((size_t)128 * BB * NPT * 4));
    size_t required = off;

    if (ws_size < required) {
        k_sentinel<<<1, 64, 0, stream>>>((float*)d_out);
        return;
    }

    float* h0  = regA;
    float* Zc3 = regA;
    float* hfp = ZA;                          // 160*FPCOLS
    float* Zf0 = ZA + (size_t)160 * FPCOLS;   // 128*FPCOLS
    float* Zc1 = ZA + (size_t)(160 + 128) * FPCOLS;
    float* Zf1 = ZB;
    float* Zc2 = ZB + (size_t)128 * FPCOLS;

    float* st[7];
    for (int l = 0; l < 7; ++l) st[l] = stats + (size_t)l * 2 * CSTR;
    const double nSA = (double)SACOLS, nFP = (double)FPCOLS;
    const int nbSA = SACOLS / 64;   // 2048
    const int nbFP = FPCOLS / 64;   // 512

    // ---- geometry ----
    k_fps<<<BB, 256, 0, stream>>>(xyz, new_xyz);
    k_ballquery<<<(BB * NPT) / 4, 256, 0, stream>>>(xyz, new_xyz, gidx);
    k_group<<<SACOLS / 256, 256, 0, stream>>>(xyz, feats, new_xyz, gidx, h0);

    // ---- SA MLP (BN stats fused into conv epilogue; parallel finalize) ----
    k_conv<<<dim3(SACOLS / 64, 2), 256, 0, stream>>>(h0, W_sa0, nullptr, nullptr, nullptr, ZA, part, 35, 128, SACOLS, 0);
    k_stats_final<<<128, 256, 0, stream>>>(part, g_sa0, b_sa0, st[0], st[0] + CSTR, nbSA, nSA);

    k_conv<<<dim3(SACOLS / 64, 2), 256, 0, stream>>>(ZA, W_sa1, nullptr, st[0], st[0] + CSTR, ZB, part, 128, 128, SACOLS, 1);
    k_stats_final<<<128, 256, 0, stream>>>(part, g_sa1, b_sa1, st[1], st[1] + CSTR, nbSA, nSA);

    k_conv<<<dim3(SACOLS / 64, 2), 256, 0, stream>>>(ZB, W_sa2, nullptr, st[1], st[1] + CSTR, ZA, part, 128, 128, SACOLS, 1);
    k_stats_final<<<128, 256, 0, stream>>>(part, g_sa2, b_sa2, st[2], st[2] + CSTR, nbSA, nSA);

    k_maxpool<<<(128 * BB * NPT) / 256, 256, 0, stream>>>(ZA, st[2], st[2] + CSTR, feat_sa);

    // ---- 3-NN interpolation + concat ----
    k_3nn<<<FPCOLS / 256, 256, 0, stream>>>(xyz, new_xyz, idx3, w3);
    k_hfp<<<FPCOLS / 256, 256, 0, stream>>>(feats, feat_sa, idx3, w3, hfp);

    // ---- FP MLP + vote head ----
    k_conv<<<dim3(FPCOLS / 64, 2), 256, 0, stream>>>(hfp, W_fp0, nullptr, nullptr, nullptr, Zf0, part, 160, 128, FPCOLS, 0);
    k_stats_final<<<128, 256, 0, stream>>>(part, g_fp0, b_fp0, st[3], st[3] + CSTR, nbFP, nFP);

    k_conv<<<dim3(FPCOLS / 64, 2), 256, 0, stream>>>(Zf0, W_fp1, nullptr, st[3], st[3] + CSTR, Zf1, part, 128, 128, FPCOLS, 1);
    k_stats_final<<<128, 256, 0, stream>>>(part, g_fp1, b_fp1, st[4], st[4] + CSTR, nbFP, nFP);

    k_conv<<<dim3(FPCOLS / 64, 2), 256, 0, stream>>>(Zf1, Wc1, bc1, st[4], st[4] + CSTR, Zc1, part, 128, 128, FPCOLS, 1);
    k_stats_final<<<128, 256, 0, stream>>>(part, g1, b1, st[5], st[5] + CSTR, nbFP, nFP);

    k_conv<<<dim3(FPCOLS / 64, 2), 256, 0, stream>>>(Zc1, Wc2, bc2, st[5], st[5] + CSTR, Zc2, part, 128, 128, FPCOLS, 1);
    k_stats_final<<<128, 256, 0, stream>>>(part, g2, b2, st[6], st[6] + CSTR, nbFP, nFP);

    k_conv<<<dim3(FPCOLS / 64, 3), 256, 0, stream>>>(Zc2, Wc3, bc3, st[6], st[6] + CSTR, Zc3, nullptr, 128, 132, FPCOLS, 1);

    // ---- outputs (FLOAT32) ----
    k_outputs<<<FPCOLS / 256, 256, 0, stream>>>(xyz, Zc3, Zf1, st[4], st[4] + CSTR, (float*)d_out);
}